// Round 1
// 248.754 us; speedup vs baseline: 1.0909x; 1.0909x over previous
//
#include <hip/hip_runtime.h>
#include <hip/hip_bf16.h>

typedef __attribute__((ext_vector_type(4))) float v4f;
typedef __attribute__((ext_vector_type(8))) short v8s;
typedef __attribute__((ext_vector_type(4))) unsigned v4u;
typedef __attribute__((ext_vector_type(2))) unsigned v2u;

// full RNE fp32->bf16 (prep kernel only)
__device__ __forceinline__ short f2bf(float f) {
  union { float f; unsigned u; } v; v.f = f;
  unsigned r = v.u + 0x7FFFu + ((v.u >> 16) & 1u);
  return (short)(r >> 16);
}
// packed 2xfp32 -> bf16x2, single v_cvt_pk_bf16_f32
__device__ __forceinline__ unsigned pk2(float a, float b) {
  union { __hip_bfloat162 h; unsigned u; } c;
  c.h = __float22bfloat162_rn(make_float2(a, b));
  return c.u;
}

// Pack W1 [128x256] and W2 [256x256] (row-major [k][n], fp32) into bf16 MFMA
// A-operand fragment order for the transposed product (W^T as A):
//   lane l of fragment (mt, kt) holds A'[n = mt*16 + (l&15)][k = kt*32 + (l>>4)*8 + j]
__global__ void pack_weights(const float* __restrict__ W1, const float* __restrict__ W2,
                             short* __restrict__ pW1, short* __restrict__ pW2) {
  int tid = blockIdx.x * 256 + threadIdx.x;
  if (tid < 32768) {
    int j = tid & 7, l = (tid >> 3) & 63, frag = tid >> 9;
    int mt = frag >> 2, kt = frag & 3;
    int n = mt * 16 + (l & 15);
    int k = kt * 32 + ((l >> 4) * 8) + j;
    pW1[tid] = f2bf(W1[k * 256 + n]);
  } else if (tid < 98304) {
    int t2 = tid - 32768;
    int j = t2 & 7, l = (t2 >> 3) & 63, frag = t2 >> 9;
    int mt = frag >> 3, kt = frag & 7;
    int n = mt * 16 + (l & 15);
    int k = kt * 32 + ((l >> 4) * 8) + j;
    pW2[t2] = f2bf(W2[k * 256 + n]);
  }
}

#define LDX_S 136   // 128 + 8 pad shorts  (2-way max per quarter-wave on b128 reads)
#define LDH_S 264   // 256 + 8 pad shorts
#define LDP_S 20    // 16 slots + 4 pad floats
#define XBUF (64 * LDX_S)   // 8704 shorts / buffer
#define HBUF (64 * LDH_S)   // 16896 shorts / buffer
#define PBUF (64 * LDP_S)   // 1280 floats / buffer
#define SMEM_BYTES (2*XBUF*2 + 2*HBUF*2 + 2*PBUF*4)   // 112640

// v9: wave-specialized producer/consumer. Rationale: v8 was LDS-read bound --
// all 8 waves (mi=2) re-read identical B fragments (X and H tiles): 384
// ds_read_b128/tile ~ 4.6K cyc > MFMA 3.7K cyc. Now 4 "A" waves hold all of
// W1 (mi=4, 64 VGPR) doing gather+L1, 4 "B" waves hold all of W2 (mi=4,
// 128 VGPR) doing L2+W3-fold: B-reads halve to 192 b128/tile (~2.3K cyc),
// MFMA pipe (3.7K cyc/tile) becomes the binding resource.
// Role map (w&1)^((w>>2)&1): one A + one B wave per SIMD under both i%4 and
// i/2 wave->SIMD conventions -> balanced per-SIMD MFMA load.
// Same single-barrier 3-deep pipeline as v8, phase k:
//   A: commit X(t_k) | prefetch t_{k+1} | (wg0) store P(t_{k-3}) | L1 t_{k-1}
//   B: L2+L3 of t_{k-2}
// Both role branches run identical k-loops -> equal __syncthreads counts.
// ni is processed in 2 halves so live acc = 32 VGPR (keeps both paths <256).
__global__ __launch_bounds__(512, 2) void mlp_v9(
    const float* __restrict__ xu, const float* __restrict__ xm,
    const void* __restrict__ eidx,
    const short* __restrict__ pW1, const short* __restrict__ pW2,
    const float* __restrict__ b1, const float* __restrict__ b2,
    const float* __restrict__ W3, const float* __restrict__ b3,
    float* __restrict__ out, int E)
{
  extern __shared__ __align__(16) char smem[];
  short* ldsX = (short*)smem;                       // [2][XBUF]
  short* ldsH = (short*)(smem + 2 * XBUF * 2);      // [2][HBUF]
  float* ldsP = (float*)(smem + 2 * XBUF * 2 + 2 * HBUF * 2); // [2][PBUF]

  const int t    = threadIdx.x;
  const int w    = t >> 6;
  const int lane = t & 63;
  const int quad = lane >> 4;
  const int lp   = lane & 15;
  const int wg   = w >> 1;                                // rank within role group (0..3)
  const bool isA = (((w & 1) ^ ((w >> 2) & 1)) == 0);     // waves {0,2,5,7}=A, {1,3,4,6}=B

  // ---- index dtype detection: int64 iff odd 32-bit words are all zero
  const unsigned* ew = (const unsigned*)eidx;
  unsigned oddw = (lane < 32) ? ew[2 * lane + 1] : 0u;
  const bool i64 = (__ballot(oddw != 0u) == 0ull);

  const int ntiles = (E + 63) >> 6;
  const int S   = (int)gridDim.x;
  const int bid = (int)blockIdx.x;
  const int Tb  = (ntiles - bid + S - 1) / S;   // tiles this block owns (>=1)
  const float bias3 = b3[0];

  if (isA) {
    // ================= producer: gather + layer 1 (+ store on wg==0) ======
    const v8s* w1v = (const v8s*)pW1;
    v8s rW1[4][4];                      // 64 VGPR: hidden rows wg*64 .. wg*64+63
#pragma unroll
    for (int mi = 0; mi < 4; ++mi)
#pragma unroll
      for (int kt = 0; kt < 4; ++kt)
        rW1[mi][kt] = w1v[(((wg * 4 + mi) * 4) + kt) * 64 + lane];
    v4f rb1[4];
#pragma unroll
    for (int mi = 0; mi < 4; ++mi)
      rb1[mi] = *(const v4f*)(b1 + wg * 64 + mi * 16 + quad * 4);

    // gather: 4 threads/edge, 16 feats/side each
    const int ra = wg * 64 + lane;      // A-rank 0..255
    const int gi = ra >> 2, gq = ra & 3;

    auto loadIdx = [&](int tl, int& row, int& col) {
      int gE = tl * 64 + gi;
      if (gE >= E || gE < 0) gE = 0;
      if (i64) {
        const long long* p = (const long long*)eidx;
        row = (int)p[gE]; col = (int)p[(long long)E + gE];
      } else {
        const int* p = (const int*)eidx;
        row = p[gE]; col = p[E + gE];
      }
    };

    v4f U0, U1, U2, U3, M0, M1, M2, M3;
    auto issueUM = [&](int row, int col) {
      const v4f* pu = (const v4f*)(xu + (size_t)row * 64 + gq * 16);
      const v4f* pm = (const v4f*)(xm + (size_t)col * 64 + gq * 16);
      U0 = pu[0]; U1 = pu[1]; U2 = pu[2]; U3 = pu[3];
      M0 = pm[0]; M1 = pm[1]; M2 = pm[2]; M3 = pm[3];
    };

    int rowN, colN;
    loadIdx(bid, rowN, colN);
    issueUM(rowN, colN);
    loadIdx(bid + S, rowN, colN);

    for (int k = 0; k <= Tb + 2; ++k) {
      __syncthreads();
      const int pb = k & 1;
      const int tg = bid + k * S;

      // ---- commit prefetched features -> ldsX[pb]
      if (k < Tb) {
        short* px = &ldsX[pb * XBUF + gi * LDX_S + gq * 16];
        v4u a0 = { pk2(U0[0], U0[1]), pk2(U0[2], U0[3]),
                   pk2(U1[0], U1[1]), pk2(U1[2], U1[3]) };
        v4u a1 = { pk2(U2[0], U2[1]), pk2(U2[2], U2[3]),
                   pk2(U3[0], U3[1]), pk2(U3[2], U3[3]) };
        v4u c0 = { pk2(M0[0], M0[1]), pk2(M0[2], M0[3]),
                   pk2(M1[0], M1[1]), pk2(M1[2], M1[3]) };
        v4u c1 = { pk2(M2[0], M2[1]), pk2(M2[2], M2[3]),
                   pk2(M3[0], M3[1]), pk2(M3[2], M3[3]) };
        *(v4u*)(px)      = a0;  *(v4u*)(px + 8)  = a1;   // user  -> k 0..63
        *(v4u*)(px + 64) = c0;  *(v4u*)(px + 72) = c1;   // movie -> k 64..127
      }
      // ---- prefetch features(t_{k+1}), indices(t_{k+2})
      if (k + 1 < Tb) {
        issueUM(rowN, colN);
        loadIdx(tg + 2 * S, rowN, colN);
      }

      // ---- reduce + store tile t3 from ldsP[pb^1] (wave wg==0, lane = edge)
      const int t3 = tg - 3 * S;
      if (t3 >= 0 && wg == 0) {
        const v4f* pp = (const v4f*)&ldsP[(pb ^ 1) * PBUF + lane * LDP_S];
        float r = bias3;
#pragma unroll
        for (int c = 0; c < 4; ++c) {
          v4f p = pp[c];
          r += (p[0] + p[1]) + (p[2] + p[3]);
        }
        int o = t3 * 64 + lane;
        if (o < E) out[o] = r;
      }

      // ---- layer 1 of t1 : ldsX[pb^1] -> ldsH[pb^1]
      const int t1 = tg - S;
      if (t1 >= 0 && t1 < ntiles) {
        const short* xb = &ldsX[(pb ^ 1) * XBUF];
        short* hb = &ldsH[(pb ^ 1) * HBUF];
#pragma unroll 1
        for (int nh = 0; nh < 2; ++nh) {       // ni halves: acc live = 32 VGPR
          v4f acc[4][2];
#pragma unroll
          for (int mi = 0; mi < 4; ++mi) { acc[mi][0] = rb1[mi]; acc[mi][1] = rb1[mi]; }
          __builtin_amdgcn_s_setprio(1);
#pragma unroll
          for (int kt = 0; kt < 4; ++kt) {
            v8s bf0 = *(const v8s*)&xb[((nh * 2 + 0) * 16 + lp) * LDX_S + kt * 32 + quad * 8];
            v8s bf1 = *(const v8s*)&xb[((nh * 2 + 1) * 16 + lp) * LDX_S + kt * 32 + quad * 8];
#pragma unroll
            for (int mi = 0; mi < 4; ++mi) {
              acc[mi][0] = __builtin_amdgcn_mfma_f32_16x16x32_bf16(rW1[mi][kt], bf0, acc[mi][0], 0, 0, 0);
              acc[mi][1] = __builtin_amdgcn_mfma_f32_16x16x32_bf16(rW1[mi][kt], bf1, acc[mi][1], 0, 0, 0);
            }
          }
          __builtin_amdgcn_s_setprio(0);
#pragma unroll
          for (int mi = 0; mi < 4; ++mi) {
            int nh0 = wg * 64 + mi * 16 + quad * 4;
#pragma unroll
            for (int nj = 0; nj < 2; ++nj) {
              int e = (nh * 2 + nj) * 16 + lp;
              v4f v = acc[mi][nj];
              v2u pw; pw.x = pk2(fmaxf(v[0], 0.f), fmaxf(v[1], 0.f));
              pw.y = pk2(fmaxf(v[2], 0.f), fmaxf(v[3], 0.f));
              *(v2u*)&hb[e * LDH_S + nh0] = pw;   // ds_write_b64
            }
          }
        }
      }
    }
  } else {
    // ================= consumer: layer 2 + bias/ReLU + W3 fold ============
    const v8s* w2v = (const v8s*)pW2;
    v8s rW2[4][8];                      // 128 VGPR: out rows wg*64 .. wg*64+63
#pragma unroll
    for (int mi = 0; mi < 4; ++mi)
#pragma unroll
      for (int kt = 0; kt < 8; ++kt)
        rW2[mi][kt] = w2v[(((wg * 4 + mi) * 8) + kt) * 64 + lane];
    v4f rb2[4], rw3[4];
#pragma unroll
    for (int mi = 0; mi < 4; ++mi) {
      int nh0 = wg * 64 + mi * 16 + quad * 4;
      rb2[mi] = *(const v4f*)(b2 + nh0);
      rw3[mi] = *(const v4f*)(W3 + nh0);   // W3 kept fp32 (precision)
    }

    for (int k = 0; k <= Tb + 2; ++k) {
      __syncthreads();
      const int pb = k & 1;
      const int tg = bid + k * S;
      const int t2 = tg - 2 * S;
      if (t2 >= 0 && t2 < ntiles) {
        const short* hbr = &ldsH[pb * HBUF];
        float* pPw = &ldsP[pb * PBUF];
#pragma unroll 1
        for (int nh = 0; nh < 2; ++nh) {       // ni halves: acc live = 32 VGPR
          v4f acc2[4][2];
#pragma unroll
          for (int mi = 0; mi < 4; ++mi) { acc2[mi][0] = rb2[mi]; acc2[mi][1] = rb2[mi]; }
          __builtin_amdgcn_s_setprio(1);
#pragma unroll
          for (int kt = 0; kt < 8; ++kt) {
            v8s bf0 = *(const v8s*)&hbr[((nh * 2 + 0) * 16 + lp) * LDH_S + kt * 32 + quad * 8];
            v8s bf1 = *(const v8s*)&hbr[((nh * 2 + 1) * 16 + lp) * LDH_S + kt * 32 + quad * 8];
#pragma unroll
            for (int mi = 0; mi < 4; ++mi) {
              acc2[mi][0] = __builtin_amdgcn_mfma_f32_16x16x32_bf16(rW2[mi][kt], bf0, acc2[mi][0], 0, 0, 0);
              acc2[mi][1] = __builtin_amdgcn_mfma_f32_16x16x32_bf16(rW2[mi][kt], bf1, acc2[mi][1], 0, 0, 0);
            }
          }
          __builtin_amdgcn_s_setprio(0);
          float s0 = 0.f, s1 = 0.f;
#pragma unroll
          for (int mi = 0; mi < 4; ++mi) {
#pragma unroll
            for (int r = 0; r < 4; ++r) {
              s0 += fmaxf(acc2[mi][0][r], 0.f) * rw3[mi][r];
              s1 += fmaxf(acc2[mi][1][r], 0.f) * rw3[mi][r];
            }
          }
          int e0 = (nh * 2 + 0) * 16 + lp, e1 = (nh * 2 + 1) * 16 + lp;
          pPw[e0 * LDP_S + wg * 4 + quad] = s0;
          pPw[e1 * LDP_S + wg * 4 + quad] = s1;
        }
      }
    }
  }
}

extern "C" void kernel_launch(void* const* d_in, const int* in_sizes, int n_in,
                              void* d_out, int out_size, void* d_ws, size_t ws_size,
                              hipStream_t stream) {
  const float* xu  = (const float*)d_in[0];
  const float* xm  = (const float*)d_in[1];
  const void*  ei  = d_in[2];
  const float* W1  = (const float*)d_in[3];
  const float* b1  = (const float*)d_in[4];
  const float* W2  = (const float*)d_in[5];
  const float* b2  = (const float*)d_in[6];
  const float* W3  = (const float*)d_in[7];
  const float* b3  = (const float*)d_in[8];
  float* out = (float*)d_out;

  const int E = in_sizes[2] / 2;

  short* pW1 = (short*)d_ws;          // 64 KB
  short* pW2 = pW1 + 32768;           // 128 KB

  hipLaunchKernelGGL(pack_weights, dim3(384), dim3(256), 0, stream, W1, W2, pW1, pW2);

  // 110 KB dynamic LDS (> 64 KB static limit); idempotent, graph-capture-safe
  hipFuncSetAttribute((const void*)mlp_v9,
                      hipFuncAttributeMaxDynamicSharedMemorySize, SMEM_BYTES);

  const int ntiles = (E + 63) / 64;
  const int nblk = ntiles < 256 ? ntiles : 256;
  hipLaunchKernelGGL(mlp_v9, dim3(nblk), dim3(512), SMEM_BYTES, stream,
                     xu, xm, ei, pW1, pW2, b1, b2, W3, b3, out, E);
}